// Round 5
// baseline (669.286 us; speedup 1.0000x reference)
//
#include <hip/hip_runtime.h>
#include <math.h>

// Problem constants
constexpr int B = 32, T = 2048, P = 128, K = 256, R = 8, M = 64;
constexpr int BT = B * T;                 // 65536 rows
constexpr int TAU = 5;
constexpr int NSEG = (T + TAU - 1) / TAU; // 410 segments
constexpr float INV_TAU_X = 1.0f / 100.0f;
constexpr float INV_TAU_Z = 1.0f / 100.0f;

typedef short bf16x4 __attribute__((ext_vector_type(4)));
typedef short bf16x8 __attribute__((ext_vector_type(8)));
typedef float f32x4 __attribute__((ext_vector_type(4)));

// fp32 <-> bf16 (RNE)
static __device__ __forceinline__ short f2bf(float f) {
  unsigned u = __builtin_bit_cast(unsigned, f);
  u += 0x7FFF + ((u >> 16) & 1);
  return (short)(u >> 16);
}
static __device__ __forceinline__ float bf2f(short h) {
  unsigned u = ((unsigned)(unsigned short)h) << 16;
  return __builtin_bit_cast(float, u);
}

// fast transcendentals (v_exp + v_rcp, ~1e-6 rel — invisible vs 2e-2 thresh)
static __device__ __forceinline__ float tanh_fast(float x) {
  const float e = __expf(2.f * x);
  return 1.f - 2.f * __builtin_amdgcn_rcpf(e + 1.f);
}
static __device__ __forceinline__ float sigmoid_fast(float x) {
  return __builtin_amdgcn_rcpf(1.f + __expf(-x));
}

// ---------------------------------------------------------------------------
// 64-lane all-reduce (sum) for 8 values. Stages 1-4 are the rocPRIM-standard
// gfx9 DPP ladder (all-VALU); stage 5 = ds_swizzle 0x401F (xor16), stage 6 =
// __shfl_xor 32. NOTE: gfx950 permlane16/32_swap builtins produced wrong
// sums here (r1 fail) — semantics differ from the assumed two-reg swap.
// ---------------------------------------------------------------------------
template <int CTRL>
static __device__ __forceinline__ float dppadd(float p) {
  return p + __builtin_bit_cast(
                 float, __builtin_amdgcn_update_dpp(
                            0, __builtin_bit_cast(int, p), CTRL, 0xF, 0xF, true));
}

static __device__ __forceinline__ void allreduce8(float p[R]) {
#pragma unroll
  for (int r = 0; r < R; ++r) p[r] = dppadd<0xB1>(p[r]);   // quad_perm [1,0,3,2]
#pragma unroll
  for (int r = 0; r < R; ++r) p[r] = dppadd<0x4E>(p[r]);   // quad_perm [2,3,0,1]
#pragma unroll
  for (int r = 0; r < R; ++r) p[r] = dppadd<0x141>(p[r]);  // row_half_mirror
#pragma unroll
  for (int r = 0; r < R; ++r) p[r] = dppadd<0x140>(p[r]);  // row_mirror
#pragma unroll
  for (int r = 0; r < R; ++r)                              // xor 16 (in-half)
    p[r] += __builtin_bit_cast(float, __builtin_amdgcn_ds_swizzle(
                                          __builtin_bit_cast(int, p[r]), 0x401F));
#pragma unroll
  for (int r = 0; r < R; ++r)                              // xor 32 (cross-half)
    p[r] += __shfl_xor(p[r], 32, 64);
}

// ---------------------------------------------------------------------------
// Generic fp32 -> split bf16 (hi/lo) elementwise kernel (weights only now).
// ---------------------------------------------------------------------------
__global__ __launch_bounds__(256) void split_kernel(
    const float* __restrict__ in, short* __restrict__ h,
    short* __restrict__ l, int n4) {
  const int i = blockIdx.x * 256 + threadIdx.x;
  if (i >= n4) return;
  const float4 v = ((const float4*)in)[i];
  const float f[4] = {v.x, v.y, v.z, v.w};
  bf16x4 ph, pl;
#pragma unroll
  for (int q = 0; q < 4; ++q) {
    ph[q] = f2bf(f[q]);
    pl[q] = f2bf(f[q] - bf2f(ph[q]));
  }
  ((bf16x4*)h)[i] = ph;
  ((bf16x4*)l)[i] = pl;
}

// Batched split of the 8 weight matrices into one region: weight w's hi at
// dst+hoff[w], lo at dst+hoff[w]+4*n4[w].
struct W8 {
  const float* src[8];
  unsigned hoff[8];  // in shorts
  unsigned n4[8];
};
__global__ __launch_bounds__(256) void split8_kernel(W8 p, short* __restrict__ dst) {
  const int w = blockIdx.y;
  const int i = blockIdx.x * 256 + threadIdx.x;
  if (i >= (int)p.n4[w]) return;
  const float4 v = ((const float4*)p.src[w])[i];
  const float f[4] = {v.x, v.y, v.z, v.w};
  bf16x4 ph, pl;
#pragma unroll
  for (int q = 0; q < 4; ++q) {
    ph[q] = f2bf(f[q]);
    pl[q] = f2bf(f[q] - bf2f(ph[q]));
  }
  *(bf16x4*)&dst[p.hoff[w] + i * 4] = ph;
  *(bf16x4*)&dst[p.hoff[w] + p.n4[w] * 4 + i * 4] = pl;
}

// ---------------------------------------------------------------------------
// C = tanh(A @ W^T + bias), split-bf16 MFMA (hh + lh + hl, fp32 acc).
//
// r5: NO-LDS register-direct GEMM. r3/r4 pipelining never beat the plain
// structure because the waves idled >90% inside stage->barrier->compute
// lockstep at 8 waves/CU. This problem is weight-stationary tiny-K: B is
// <=256 KB (L2-resident for every block) and the mfma_16x16x32 fragment
// layout (row/col = lane&15, k-chunk = 8*(lane>>4)) is loadable straight
// from row-major global memory as ONE dwordx4 per lane (64 B coalesced
// segments per 4-lane group). So: zero LDS, zero barriers; A and B frags
// load global->VGPR; the compiler pipelines ~16 independent loads/K-tile
// freely across iterations.
//
// A is fp32 (4 B/elem == h+l bf16 pair bytes) and is split to h/l IN
// REGISTERS with exactly split_kernel's rounding -> the MFMA consumes
// bit-identical operands in the identical k-order (k0 ascending 32-steps;
// hh, lh, hl per acc) => results match the pre-split version exactly.
// B (weights) stays pre-split bf16 (split8).
// Block tile 128 x BN, 4 waves (warpM=wave&1, warpN=wave>>1).
// ---------------------------------------------------------------------------
template <int KIN, int KOUT, int BN>
__global__ __launch_bounds__(256, 2) void gemm_reg(
    const float* __restrict__ A, const short* __restrict__ Bh,
    const short* __restrict__ Bl, const float* __restrict__ bias,
    float* __restrict__ C) {
  constexpr int WNT = BN / 32;  // 16-col sub-tiles per wave
  static_assert(KIN % 32 == 0, "K tiling");

  const int tid = threadIdx.x;
  const int wave = tid >> 6, lane = tid & 63;
  const int l16 = lane & 15, quad = lane >> 4;
  const int warpM = wave & 1, warpN = wave >> 1;
  const int row0 = blockIdx.x * 128 + warpM * 64;
  const int col0 = blockIdx.y * BN + warpN * WNT * 16;

  f32x4 acc[4][WNT];
#pragma unroll
  for (int i = 0; i < 4; ++i)
#pragma unroll
    for (int j = 0; j < WNT; ++j) acc[i][j] = (f32x4){0.f, 0.f, 0.f, 0.f};

  // per-lane fragment base pointers (lane's k-chunk = quad*8)
  const float* arow[4];
#pragma unroll
  for (int i = 0; i < 4; ++i)
    arow[i] = A + (size_t)(row0 + i * 16 + l16) * KIN + quad * 8;
  const short* bch[WNT];
  const short* bcl[WNT];
#pragma unroll
  for (int j = 0; j < WNT; ++j) {
    const size_t off = (size_t)(col0 + j * 16 + l16) * KIN + quad * 8;
    bch[j] = Bh + off;
    bcl[j] = Bl + off;
  }

#pragma unroll 2
  for (int k0 = 0; k0 < KIN; k0 += 32) {
    bf16x8 bh[WNT], bl[WNT];
#pragma unroll
    for (int j = 0; j < WNT; ++j) {
      bh[j] = *(const bf16x8*)(bch[j] + k0);
      bl[j] = *(const bf16x8*)(bcl[j] + k0);
    }
#pragma unroll
    for (int i = 0; i < 4; ++i) {
      const f32x4 a0 = *(const f32x4*)(arow[i] + k0);
      const f32x4 a1 = *(const f32x4*)(arow[i] + k0 + 4);
      bf16x8 ah, al;
#pragma unroll
      for (int e = 0; e < 4; ++e) {
        ah[e] = f2bf(a0[e]);
        al[e] = f2bf(a0[e] - bf2f(ah[e]));
        ah[4 + e] = f2bf(a1[e]);
        al[4 + e] = f2bf(a1[e] - bf2f(ah[4 + e]));
      }
#pragma unroll
      for (int j = 0; j < WNT; ++j) {
        acc[i][j] = __builtin_amdgcn_mfma_f32_16x16x32_bf16(ah, bh[j],
                                                            acc[i][j], 0, 0, 0);
        acc[i][j] = __builtin_amdgcn_mfma_f32_16x16x32_bf16(al, bh[j],
                                                            acc[i][j], 0, 0, 0);
        acc[i][j] = __builtin_amdgcn_mfma_f32_16x16x32_bf16(ah, bl[j],
                                                            acc[i][j], 0, 0, 0);
      }
    }
  }

  // Epilogue. C/D map: col = lane&15, row = quad*4 + reg. fp32 stores.
#pragma unroll
  for (int j = 0; j < WNT; ++j) {
    const int col = col0 + j * 16 + l16;
    const float bj = bias[col];
#pragma unroll
    for (int i = 0; i < 4; ++i) {
      const int rbase = row0 + i * 16 + quad * 4;
#pragma unroll
      for (int r = 0; r < 4; ++r)
        C[(size_t)(rbase + r) * KOUT + col] = tanh_fast(acc[i][j][r] + bj);
    }
  }
}

// ---------------------------------------------------------------------------
// Scan: reset every TAU=5 -> independent (batch, segment) chains; one wave
// per chain, 8 waves/block, NO inner barriers (tz_s rows wave-private).
// x_seq is now fp32 (X0); scan runs IN-PLACE on it (each wave reads only
// its seed row 5*seg before writing rows 5seg..5seg+4; rows disjoint).
// Reductions: rocPRIM DPP ladder + ds_swizzle/shfl (r2-proven). L/Rm staged
// native [k][r] -> 32 B contiguous rank-8 slices (ds_read_b128). Wz staged
// stride-68; tz broadcast via float4; Az cached in registers.
// ---------------------------------------------------------------------------
__global__ __launch_bounds__(512) void scan_kernel(
    float* xs,                                 // fp32 x_seq / x_states (in-place)
    const float* __restrict__ z_seq,           // fp32
    const float* __restrict__ Lm, const float* __restrict__ Rm,
    const float* __restrict__ Wz, const float* __restrict__ Az_w,
    const float* __restrict__ Az_b,
    float* __restrict__ z_pred) {
  __shared__ __align__(16) float Wz_s[M][68];  // stride 68: 16B rows, balanced
  __shared__ __align__(16) float Ls[K * R];    // native [k][r] layout
  __shared__ __align__(16) float Rs[K * R];    // native [k][r] layout
  __shared__ __align__(16) float tz_s[8][M];   // per-wave rows (256 B aligned)

  const int tid = threadIdx.x;
  for (int i = tid; i < M * M; i += 512) Wz_s[i >> 6][i & 63] = Wz[i];
  // K*R = 2048 floats = 512 float4 -> exactly one per thread
  ((float4*)Ls)[tid] = ((const float4*)Lm)[tid];
  ((float4*)Rs)[tid] = ((const float4*)Rm)[tid];
  __syncthreads();

  const int wave = tid >> 6;
  const int lane = tid & 63;
  const int chain = blockIdx.x * 8 + wave;
  const int b = chain / NSEG;
  const int seg = chain % NSEG;
  const int t0 = seg * TAU;

  // per-lane register caches (reused all 5 steps)
  float azw[R], azb[R];
#pragma unroll
  for (int r = 0; r < R; ++r) {
    azw[r] = Az_w[r * M + lane];
    azb[r] = Az_b[r];
  }

  float x[4], z;
  {
    const size_t base = ((size_t)b * T + t0);
#pragma unroll
    for (int j = 0; j < 4; ++j) x[j] = xs[base * K + lane + 64 * j];
    z = z_seq[base * M + lane];
  }

  const float4* wrow = (const float4*)&Wz_s[lane][0];  // lane*272 B, 16-al.
  const float4* trow = (const float4*)&tz_s[wave][0];

  for (int tt = 0; tt < TAU; ++tt) {
    const int t = t0 + tt;
    // z update: z += (tanh(z) @ Wz^T - z)/100
    const float tz = tanh_fast(z);
    tz_s[wave][lane] = tz;  // wave-private row; intra-wave DS order suffices
    float zacc = 0.f;
#pragma unroll
    for (int j = 0; j < 16; ++j) {
      const float4 w = wrow[j], tv = trow[j];
      zacc += w.x * tv.x + w.y * tv.y + w.z * tv.z + w.w * tv.w;
    }
    const float znew = z + (zacc - z) * INV_TAU_Z;

    // s = sigmoid(z_new @ Az^T + b)  — DPP/swizzle butterfly reduce
    float s[R];
#pragma unroll
    for (int r = 0; r < R; ++r) s[r] = znew * azw[r];
    allreduce8(s);
#pragma unroll
    for (int r = 0; r < R; ++r) s[r] = sigmoid_fast(s[r] + azb[r]);

    // x update: u = tanh(x) @ L ; v = u*s ; x += (v @ Rm^T - x)/100
    float tx4[4];
#pragma unroll
    for (int j = 0; j < 4; ++j) tx4[j] = tanh_fast(x[j]);
    float v[R];
#pragma unroll
    for (int r = 0; r < R; ++r) v[r] = 0.f;
#pragma unroll
    for (int j = 0; j < 4; ++j) {
      const int kb = (lane + 64 * j) * 8;
      const f32x4 la = *(const f32x4*)&Ls[kb];
      const f32x4 lb = *(const f32x4*)&Ls[kb + 4];
      const float txj = tx4[j];
      v[0] += txj * la[0]; v[1] += txj * la[1];
      v[2] += txj * la[2]; v[3] += txj * la[3];
      v[4] += txj * lb[0]; v[5] += txj * lb[1];
      v[6] += txj * lb[2]; v[7] += txj * lb[3];
    }
    allreduce8(v);
#pragma unroll
    for (int r = 0; r < R; ++r) v[r] *= s[r];
#pragma unroll
    for (int j = 0; j < 4; ++j) {
      const int kb = (lane + 64 * j) * 8;
      const f32x4 ra = *(const f32x4*)&Rs[kb];
      const f32x4 rb = *(const f32x4*)&Rs[kb + 4];
      const float xacc = v[0] * ra[0] + v[1] * ra[1] + v[2] * ra[2] +
                         v[3] * ra[3] + v[4] * rb[0] + v[5] * rb[1] +
                         v[6] * rb[2] + v[7] * rb[3];
      x[j] = x[j] + (xacc - x[j]) * INV_TAU_X;
    }

    if (t < T) {
      const size_t o = ((size_t)b * T + t);
#pragma unroll
      for (int j = 0; j < 4; ++j) xs[o * K + lane + 64 * j] = x[j];
      z_pred[o * M + lane] = znew;
    }
    z = znew;
  }
}

// ---------------------------------------------------------------------------
// Buffers/schedule (fp32 activations; ws = 2 x 64 MB ping-pong):
//  ws:  X0 = BT*K floats (64 MB), X1 = BT*K floats (64 MB) = 128 MiB exactly.
//  out: x_pred | x_recon | z_pred | z_seq.
//  Wr (8 split weights, 1.1 MB)  -> z_pred region  (live 1..9; scan@11 kills)
//  Z0/Z1 (z activ., fp32 16 MB)  -> X1             (live 7..9)
//  WD1 (split de1_w, 512 KB)     -> x_pred region  (live 10..12; de2p@14 kills)
//  WD2 (split de2_w, 128 KB)     -> X0 base        (live 13..14)
//  1 split8; 2 ex1 in_seq->X0; 3 ex2 X0->X1; 4 ex3 X1->X0(x_seq);
//  5 de1r X0->X1; 6 de2r X1->x_recon; 7 ez1 in_seq->Z0; 8 ez2 Z0->Z1;
//  9 ez3 Z1->z_seq; 10 split de1_w->WD1; 11 scan X0 in-place + z_pred;
//  12 de1p X0->X1 (B=WD1); 13 split de2_w->WD2; 14 de2p X1->x_pred (B=WD2)
// ---------------------------------------------------------------------------
extern "C" void kernel_launch(void* const* d_in, const int* in_sizes, int n_in,
                              void* d_out, int out_size, void* d_ws,
                              size_t ws_size, hipStream_t stream) {
  const float* in_seq = (const float*)d_in[0];
  const float* Lm    = (const float*)d_in[1];
  const float* Rm    = (const float*)d_in[2];
  const float* Wz    = (const float*)d_in[3];
  const float* Az_w  = (const float*)d_in[4];
  const float* Az_b  = (const float*)d_in[5];
  const float* ex1_w = (const float*)d_in[6];
  const float* ex1_b = (const float*)d_in[7];
  const float* ex2_w = (const float*)d_in[8];
  const float* ex2_b = (const float*)d_in[9];
  const float* ex3_w = (const float*)d_in[10];
  const float* ex3_b = (const float*)d_in[11];
  const float* ez1_w = (const float*)d_in[12];
  const float* ez1_b = (const float*)d_in[13];
  const float* ez2_w = (const float*)d_in[14];
  const float* ez2_b = (const float*)d_in[15];
  const float* ez3_w = (const float*)d_in[16];
  const float* ez3_b = (const float*)d_in[17];
  const float* de1_w = (const float*)d_in[18];
  const float* de1_b = (const float*)d_in[19];
  const float* de2_w = (const float*)d_in[20];
  const float* de2_b = (const float*)d_in[21];

  float* out = (float*)d_out;
  float* x_pred  = out;                                        // BT*P
  float* x_recon = out + (size_t)BT * P;                       // BT*P
  float* z_pred  = out + (size_t)2 * BT * P;                   // BT*M
  float* z_seq   = out + (size_t)2 * BT * P + (size_t)BT * M;  // BT*M

  float* X0 = (float*)d_ws;               // BT*K fp32 activations (64 MB)
  float* X1 = X0 + (size_t)BT * K;        // 64 MB
  float* Z0 = X1;                         // z activations inside X1 window
  float* Z1 = X1 + (size_t)BT * M;
  short* Wr  = (short*)z_pred;            // split-weight block in z_pred region
  short* WD1 = (short*)x_pred;            // de1 re-split (x_pred free till 14)
  short* WD2 = (short*)X0;                // de2 re-split (after X0 dies @12)

  // weight offsets in Wr (shorts): hi at hoff, lo at hoff + 4*n4
  const unsigned HO_EX1 = 0,      HO_EX2 = 65536,  HO_EX3 = 196608;
  const unsigned HO_DE1 = 327680, HO_DE2 = 458752;
  const unsigned HO_EZ1 = 524288, HO_EZ2 = 540672, HO_EZ3 = 548864;

  const dim3 blk(256);
  const dim3 gx(BT / 128, 2);    // KOUT=256, BN=128
  const dim3 g128(BT / 128, 1);  // KOUT=128
  const dim3 g64(BT / 128, 1);   // KOUT=64, BN=64

  // 1: split all 8 weights into Wr
  W8 w8;
  w8.src[0] = ex1_w; w8.hoff[0] = HO_EX1; w8.n4[0] = 8192;
  w8.src[1] = ex2_w; w8.hoff[1] = HO_EX2; w8.n4[1] = 16384;
  w8.src[2] = ex3_w; w8.hoff[2] = HO_EX3; w8.n4[2] = 16384;
  w8.src[3] = de1_w; w8.hoff[3] = HO_DE1; w8.n4[3] = 16384;
  w8.src[4] = de2_w; w8.hoff[4] = HO_DE2; w8.n4[4] = 8192;
  w8.src[5] = ez1_w; w8.hoff[5] = HO_EZ1; w8.n4[5] = 2048;
  w8.src[6] = ez2_w; w8.hoff[6] = HO_EZ2; w8.n4[6] = 1024;
  w8.src[7] = ez3_w; w8.hoff[7] = HO_EZ3; w8.n4[7] = 1024;
  split8_kernel<<<dim3(64, 8), blk, 0, stream>>>(w8, Wr);

  // 2-4: x encoder 128->256->256->256
  gemm_reg<128, 256, 128><<<gx, blk, 0, stream>>>(
      in_seq, Wr + HO_EX1, Wr + HO_EX1 + 32768, ex1_b, X0);
  gemm_reg<256, 256, 128><<<gx, blk, 0, stream>>>(
      X0, Wr + HO_EX2, Wr + HO_EX2 + 65536, ex2_b, X1);
  gemm_reg<256, 256, 128><<<gx, blk, 0, stream>>>(
      X1, Wr + HO_EX3, Wr + HO_EX3 + 65536, ex3_b, X0);
  // 5-6: x_recon decoder
  gemm_reg<256, 256, 128><<<gx, blk, 0, stream>>>(
      X0, Wr + HO_DE1, Wr + HO_DE1 + 65536, de1_b, X1);
  gemm_reg<256, 128, 128><<<g128, blk, 0, stream>>>(
      X1, Wr + HO_DE2, Wr + HO_DE2 + 32768, de2_b, x_recon);
  // 7-9: z encoder 128->64->64->64
  gemm_reg<128, 64, 64><<<g64, blk, 0, stream>>>(
      in_seq, Wr + HO_EZ1, Wr + HO_EZ1 + 8192, ez1_b, Z0);
  gemm_reg<64, 64, 64><<<g64, blk, 0, stream>>>(
      Z0, Wr + HO_EZ2, Wr + HO_EZ2 + 4096, ez2_b, Z1);
  gemm_reg<64, 64, 64><<<g64, blk, 0, stream>>>(
      Z1, Wr + HO_EZ3, Wr + HO_EZ3 + 4096, ez3_b, z_seq);
  // 10: split de1_w into x_pred region (z_pred/Wr dies at scan)
  split_kernel<<<dim3(64), blk, 0, stream>>>(de1_w, WD1, WD1 + 65536, 16384);
  // 11: scan (in-place on X0), z_pred out
  scan_kernel<<<dim3(B * NSEG / 8), dim3(512), 0, stream>>>(
      X0, z_seq, Lm, Rm, Wz, Az_w, Az_b, z_pred);
  // 12: de1p X0 -> X1
  gemm_reg<256, 256, 128><<<gx, blk, 0, stream>>>(
      X0, WD1, WD1 + 65536, de1_b, X1);
  // 13: split de2_w into dead X0 head
  split_kernel<<<dim3(32), blk, 0, stream>>>(de2_w, WD2, WD2 + 32768, 8192);
  // 14: de2p X1 -> x_pred
  gemm_reg<256, 128, 128><<<g128, blk, 0, stream>>>(
      X1, WD2, WD2 + 32768, de2_b, x_pred);
}

// Round 6
// 550.892 us; speedup vs baseline: 1.2149x; 1.2149x over previous
//
#include <hip/hip_runtime.h>
#include <math.h>

// Problem constants
constexpr int B = 32, T = 2048, P = 128, K = 256, R = 8, M = 64;
constexpr int BT = B * T;                 // 65536 rows
constexpr int TAU = 5;
constexpr int NSEG = (T + TAU - 1) / TAU; // 410 segments
constexpr float INV_TAU_X = 1.0f / 100.0f;
constexpr float INV_TAU_Z = 1.0f / 100.0f;

typedef short bf16x4 __attribute__((ext_vector_type(4)));
typedef short bf16x8 __attribute__((ext_vector_type(8)));
typedef float f32x4 __attribute__((ext_vector_type(4)));

// fp32 <-> bf16 (RNE)
static __device__ __forceinline__ short f2bf(float f) {
  unsigned u = __builtin_bit_cast(unsigned, f);
  u += 0x7FFF + ((u >> 16) & 1);
  return (short)(u >> 16);
}
static __device__ __forceinline__ float bf2f(short h) {
  unsigned u = ((unsigned)(unsigned short)h) << 16;
  return __builtin_bit_cast(float, u);
}

// fast transcendentals (v_exp + v_rcp, ~1e-6 rel — invisible vs 2e-2 thresh)
static __device__ __forceinline__ float tanh_fast(float x) {
  const float e = __expf(2.f * x);
  return 1.f - 2.f * __builtin_amdgcn_rcpf(e + 1.f);
}
static __device__ __forceinline__ float sigmoid_fast(float x) {
  return __builtin_amdgcn_rcpf(1.f + __expf(-x));
}

// async global->LDS, 16 B/lane; LDS dest = wave-uniform base + lane*16.
static __device__ __forceinline__ void async16(const void* g, void* l) {
  __builtin_amdgcn_global_load_lds(
      (const __attribute__((address_space(1))) void*)g,
      (__attribute__((address_space(3))) void*)l, 16, 0, 0);
}

// ---------------------------------------------------------------------------
// 64-lane all-reduce (sum) for 8 values. Stages 1-4 are the rocPRIM-standard
// gfx9 DPP ladder (all-VALU); stage 5 = ds_swizzle 0x401F (xor16), stage 6 =
// __shfl_xor 32. NOTE: gfx950 permlane16/32_swap builtins produced wrong
// sums here (r1 fail) — semantics differ from the assumed two-reg swap.
// ---------------------------------------------------------------------------
template <int CTRL>
static __device__ __forceinline__ float dppadd(float p) {
  return p + __builtin_bit_cast(
                 float, __builtin_amdgcn_update_dpp(
                            0, __builtin_bit_cast(int, p), CTRL, 0xF, 0xF, true));
}

static __device__ __forceinline__ void allreduce8(float p[R]) {
#pragma unroll
  for (int r = 0; r < R; ++r) p[r] = dppadd<0xB1>(p[r]);   // quad_perm [1,0,3,2]
#pragma unroll
  for (int r = 0; r < R; ++r) p[r] = dppadd<0x4E>(p[r]);   // quad_perm [2,3,0,1]
#pragma unroll
  for (int r = 0; r < R; ++r) p[r] = dppadd<0x141>(p[r]);  // row_half_mirror
#pragma unroll
  for (int r = 0; r < R; ++r) p[r] = dppadd<0x140>(p[r]);  // row_mirror
#pragma unroll
  for (int r = 0; r < R; ++r)                              // xor 16 (in-half)
    p[r] += __builtin_bit_cast(float, __builtin_amdgcn_ds_swizzle(
                                          __builtin_bit_cast(int, p[r]), 0x401F));
#pragma unroll
  for (int r = 0; r < R; ++r)                              // xor 32 (cross-half)
    p[r] += __shfl_xor(p[r], 32, 64);
}

// ---------------------------------------------------------------------------
// Generic fp32 -> split bf16 (hi/lo) elementwise kernel (weights only now).
// ---------------------------------------------------------------------------
__global__ __launch_bounds__(256) void split_kernel(
    const float* __restrict__ in, short* __restrict__ h,
    short* __restrict__ l, int n4) {
  const int i = blockIdx.x * 256 + threadIdx.x;
  if (i >= n4) return;
  const float4 v = ((const float4*)in)[i];
  const float f[4] = {v.x, v.y, v.z, v.w};
  bf16x4 ph, pl;
#pragma unroll
  for (int q = 0; q < 4; ++q) {
    ph[q] = f2bf(f[q]);
    pl[q] = f2bf(f[q] - bf2f(ph[q]));
  }
  ((bf16x4*)h)[i] = ph;
  ((bf16x4*)l)[i] = pl;
}

// Batched split of the 8 weight matrices into one region: weight w's hi at
// dst+hoff[w], lo at dst+hoff[w]+4*n4[w].
struct W8 {
  const float* src[8];
  unsigned hoff[8];  // in shorts
  unsigned n4[8];
};
__global__ __launch_bounds__(256) void split8_kernel(W8 p, short* __restrict__ dst) {
  const int w = blockIdx.y;
  const int i = blockIdx.x * 256 + threadIdx.x;
  if (i >= (int)p.n4[w]) return;
  const float4 v = ((const float4*)p.src[w])[i];
  const float f[4] = {v.x, v.y, v.z, v.w};
  bf16x4 ph, pl;
#pragma unroll
  for (int q = 0; q < 4; ++q) {
    ph[q] = f2bf(f[q]);
    pl[q] = f2bf(f[q] - bf2f(ph[q]));
  }
  *(bf16x4*)&dst[p.hoff[w] + i * 4] = ph;
  *(bf16x4*)&dst[p.hoff[w] + p.n4[w] * 4 + i * 4] = pl;
}

// ---------------------------------------------------------------------------
// C = tanh(A @ W^T + bias), split-bf16 MFMA (hh + lh + hl, fp32 acc).
//
// r6: A-in-LDS / B-register-direct hybrid.
//  - r5 (no LDS at all) proved the traffic model (FETCH = A read once) but
//    was latency-bound: MfmaUtil 12%, 1.8 TB/s, VGPR=96 -> no prefetch regs,
//    each K-tile ate ~900cyc HBM latency serially.
//  - Fix: stage ONLY A (fp32) through LDS: 128x32 floats = 16 KB/buffer,
//    double-buffered = 32 KB -> 3 blocks/CU (12 waves/CU, 1.5x the old
//    4-buffer layout). B frags load straight from L2 (<=256 KB resident).
//  - Counted-vmcnt pipeline (r4 lesson, fixed ordering): per tile,
//    loadB(cur) FIRST, then 4 async16 A(next) stages, then
//    s_waitcnt vmcnt(4): the 4 newest (= next-tile stages) stay in flight
//    across the barrier; B(cur)+A(cur), being older, are drained (vmcnt
//    retires in order). Main loop never drains to 0.
//  - A LDS image uses r2's PROVEN 8x16B-chunk XOR swizzle (rows are 128 B
//    here exactly as there): store chunk (l&7)^(l>>3) via pre-swizzled
//    global source (LDS dest linear); read slot = chunk ^ (l16&7).
//    <=2-way bank aliasing (free, m136).
//  - A fp32 is split to bf16 h/l IN REGISTERS with split_kernel's exact
//    rounding; float order into a0/a1 and the hh/lh/hl MFMA sequence are
//    bit-identical to r5 => identical results.
// Block tile 128 x BN, 4 waves (warpM=wave&1, warpN=wave>>1).
// ---------------------------------------------------------------------------
template <int KIN, int KOUT, int BN>
__global__ __launch_bounds__(256, 3) void gemm_als(
    const float* __restrict__ A, const short* __restrict__ Bh,
    const short* __restrict__ Bl, const float* __restrict__ bias,
    float* __restrict__ C) {
  constexpr int WNT = BN / 32;  // 16-col sub-tiles per wave
  constexpr int NT = KIN / 32;  // K tiles (BK = 32 floats)
  static_assert(KIN % 32 == 0, "K tiling");

  __shared__ float As[2][128 * 32];  // 2 x 16 KB

  const int tid = threadIdx.x;
  const int wave = tid >> 6, lane = tid & 63;
  const int l16 = lane & 15, quad = lane >> 4;
  const int sw = l16 & 7;  // read-side swizzle key
  const int warpM = wave & 1, warpN = wave >> 1;
  const int row0 = blockIdx.x * 128;
  const int col0 = blockIdx.y * BN + warpN * WNT * 16;
  // staging-side: lane covers row (8t + l>>3), fetches swizzled 16B chunk:
  const int srow = lane >> 3;                 // 0..7 within an 8-row window
  const int schunk = (lane & 7) ^ srow;       // pre-swizzled global chunk

  // stage K-tile kt of A into buffer buf (16 issues/block, 4 per wave)
  auto stage = [&](int kt, int buf) {
#pragma unroll
    for (int t = wave; t < 16; t += 4) {
      const size_t g =
          (size_t)(row0 + t * 8 + srow) * KIN + kt * 32 + schunk * 4;
      async16(&A[g], &As[buf][t * 256]);
    }
  };

  // per-lane B fragment pointers (lane's k-chunk = quad*8 shorts)
  const short* bch[WNT];
  const short* bcl[WNT];
#pragma unroll
  for (int j = 0; j < WNT; ++j) {
    const size_t off = (size_t)(col0 + j * 16 + l16) * KIN + quad * 8;
    bch[j] = Bh + off;
    bcl[j] = Bl + off;
  }

  f32x4 acc[4][WNT];
#pragma unroll
  for (int i = 0; i < 4; ++i)
#pragma unroll
    for (int j = 0; j < WNT; ++j) acc[i][j] = (f32x4){0.f, 0.f, 0.f, 0.f};

  stage(0, 0);  // prologue

  const int s0 = (2 * quad) ^ sw;      // swizzled 16B slots for this lane
  const int s1 = (2 * quad + 1) ^ sw;

  for (int it = 0; it < NT; ++it) {
    const int cur = it & 1;
    // B for current tile (L2-resident), issued BEFORE next-tile stages so
    // the counted vmcnt below also retires them.
    bf16x8 bh[WNT], bl[WNT];
#pragma unroll
    for (int j = 0; j < WNT; ++j) {
      bh[j] = *(const bf16x8*)(bch[j] + it * 32);
      bl[j] = *(const bf16x8*)(bcl[j] + it * 32);
    }
    if (it + 1 < NT) {
      stage(it + 1, cur ^ 1);
      asm volatile("s_waitcnt vmcnt(4)" ::: "memory");
    } else {
      asm volatile("s_waitcnt vmcnt(0)" ::: "memory");
    }
    __builtin_amdgcn_s_barrier();
    asm volatile("" ::: "memory");

    // compute current tile from LDS
#pragma unroll
    for (int i = 0; i < 4; ++i) {
      const int ar = warpM * 64 + i * 16 + l16;
      const f32x4 a0 = *(const f32x4*)&As[cur][ar * 32 + s0 * 4];
      const f32x4 a1 = *(const f32x4*)&As[cur][ar * 32 + s1 * 4];
      bf16x8 ah, al;
#pragma unroll
      for (int e = 0; e < 4; ++e) {
        ah[e] = f2bf(a0[e]);
        al[e] = f2bf(a0[e] - bf2f(ah[e]));
        ah[4 + e] = f2bf(a1[e]);
        al[4 + e] = f2bf(a1[e] - bf2f(ah[4 + e]));
      }
#pragma unroll
      for (int j = 0; j < WNT; ++j) {
        acc[i][j] = __builtin_amdgcn_mfma_f32_16x16x32_bf16(ah, bh[j],
                                                            acc[i][j], 0, 0, 0);
        acc[i][j] = __builtin_amdgcn_mfma_f32_16x16x32_bf16(al, bh[j],
                                                            acc[i][j], 0, 0, 0);
        acc[i][j] = __builtin_amdgcn_mfma_f32_16x16x32_bf16(ah, bl[j],
                                                            acc[i][j], 0, 0, 0);
      }
    }
    asm volatile("" ::: "memory");
    __builtin_amdgcn_s_barrier();  // buffer 'cur' free for next-next stage
  }

  // Epilogue. C/D map: col = lane&15, row = quad*4 + reg. fp32 stores.
#pragma unroll
  for (int j = 0; j < WNT; ++j) {
    const int col = col0 + j * 16 + l16;
    const float bj = bias[col];
#pragma unroll
    for (int i = 0; i < 4; ++i) {
      const int rbase = row0 + warpM * 64 + i * 16 + quad * 4;
#pragma unroll
      for (int r = 0; r < 4; ++r)
        C[(size_t)(rbase + r) * KOUT + col] = tanh_fast(acc[i][j][r] + bj);
    }
  }
}

// ---------------------------------------------------------------------------
// Scan: reset every TAU=5 -> independent (batch, segment) chains; one wave
// per chain, 8 waves/block, NO inner barriers (tz_s rows wave-private).
// x_seq is fp32 (X0); scan runs IN-PLACE on it (each wave reads only its
// seed row 5*seg before writing rows 5seg..5seg+4; rows disjoint).
// Reductions: rocPRIM DPP ladder + ds_swizzle/shfl (r2-proven). L/Rm staged
// native [k][r] -> 32 B contiguous rank-8 slices (ds_read_b128). Wz staged
// stride-68; tz broadcast via float4; Az cached in registers.
// ---------------------------------------------------------------------------
__global__ __launch_bounds__(512) void scan_kernel(
    float* xs,                                 // fp32 x_seq / x_states (in-place)
    const float* __restrict__ z_seq,           // fp32
    const float* __restrict__ Lm, const float* __restrict__ Rm,
    const float* __restrict__ Wz, const float* __restrict__ Az_w,
    const float* __restrict__ Az_b,
    float* __restrict__ z_pred) {
  __shared__ __align__(16) float Wz_s[M][68];  // stride 68: 16B rows, balanced
  __shared__ __align__(16) float Ls[K * R];    // native [k][r] layout
  __shared__ __align__(16) float Rs[K * R];    // native [k][r] layout
  __shared__ __align__(16) float tz_s[8][M];   // per-wave rows (256 B aligned)

  const int tid = threadIdx.x;
  for (int i = tid; i < M * M; i += 512) Wz_s[i >> 6][i & 63] = Wz[i];
  // K*R = 2048 floats = 512 float4 -> exactly one per thread
  ((float4*)Ls)[tid] = ((const float4*)Lm)[tid];
  ((float4*)Rs)[tid] = ((const float4*)Rm)[tid];
  __syncthreads();

  const int wave = tid >> 6;
  const int lane = tid & 63;
  const int chain = blockIdx.x * 8 + wave;
  const int b = chain / NSEG;
  const int seg = chain % NSEG;
  const int t0 = seg * TAU;

  // per-lane register caches (reused all 5 steps)
  float azw[R], azb[R];
#pragma unroll
  for (int r = 0; r < R; ++r) {
    azw[r] = Az_w[r * M + lane];
    azb[r] = Az_b[r];
  }

  float x[4], z;
  {
    const size_t base = ((size_t)b * T + t0);
#pragma unroll
    for (int j = 0; j < 4; ++j) x[j] = xs[base * K + lane + 64 * j];
    z = z_seq[base * M + lane];
  }

  const float4* wrow = (const float4*)&Wz_s[lane][0];  // lane*272 B, 16-al.
  const float4* trow = (const float4*)&tz_s[wave][0];

  for (int tt = 0; tt < TAU; ++tt) {
    const int t = t0 + tt;
    // z update: z += (tanh(z) @ Wz^T - z)/100
    const float tz = tanh_fast(z);
    tz_s[wave][lane] = tz;  // wave-private row; intra-wave DS order suffices
    float zacc = 0.f;
#pragma unroll
    for (int j = 0; j < 16; ++j) {
      const float4 w = wrow[j], tv = trow[j];
      zacc += w.x * tv.x + w.y * tv.y + w.z * tv.z + w.w * tv.w;
    }
    const float znew = z + (zacc - z) * INV_TAU_Z;

    // s = sigmoid(z_new @ Az^T + b)  — DPP/swizzle butterfly reduce
    float s[R];
#pragma unroll
    for (int r = 0; r < R; ++r) s[r] = znew * azw[r];
    allreduce8(s);
#pragma unroll
    for (int r = 0; r < R; ++r) s[r] = sigmoid_fast(s[r] + azb[r]);

    // x update: u = tanh(x) @ L ; v = u*s ; x += (v @ Rm^T - x)/100
    float tx4[4];
#pragma unroll
    for (int j = 0; j < 4; ++j) tx4[j] = tanh_fast(x[j]);
    float v[R];
#pragma unroll
    for (int r = 0; r < R; ++r) v[r] = 0.f;
#pragma unroll
    for (int j = 0; j < 4; ++j) {
      const int kb = (lane + 64 * j) * 8;
      const f32x4 la = *(const f32x4*)&Ls[kb];
      const f32x4 lb = *(const f32x4*)&Ls[kb + 4];
      const float txj = tx4[j];
      v[0] += txj * la[0]; v[1] += txj * la[1];
      v[2] += txj * la[2]; v[3] += txj * la[3];
      v[4] += txj * lb[0]; v[5] += txj * lb[1];
      v[6] += txj * lb[2]; v[7] += txj * lb[3];
    }
    allreduce8(v);
#pragma unroll
    for (int r = 0; r < R; ++r) v[r] *= s[r];
#pragma unroll
    for (int j = 0; j < 4; ++j) {
      const int kb = (lane + 64 * j) * 8;
      const f32x4 ra = *(const f32x4*)&Rs[kb];
      const f32x4 rb = *(const f32x4*)&Rs[kb + 4];
      const float xacc = v[0] * ra[0] + v[1] * ra[1] + v[2] * ra[2] +
                         v[3] * ra[3] + v[4] * rb[0] + v[5] * rb[1] +
                         v[6] * rb[2] + v[7] * rb[3];
      x[j] = x[j] + (xacc - x[j]) * INV_TAU_X;
    }

    if (t < T) {
      const size_t o = ((size_t)b * T + t);
#pragma unroll
      for (int j = 0; j < 4; ++j) xs[o * K + lane + 64 * j] = x[j];
      z_pred[o * M + lane] = znew;
    }
    z = znew;
  }
}

// ---------------------------------------------------------------------------
// Buffers/schedule (fp32 activations; ws = 2 x 64 MB ping-pong):
//  ws:  X0 = BT*K floats (64 MB), X1 = BT*K floats (64 MB) = 128 MiB exactly.
//  out: x_pred | x_recon | z_pred | z_seq.
//  Wr (8 split weights, 1.1 MB)  -> z_pred region  (live 1..9; scan@11 kills)
//  Z0/Z1 (z activ., fp32 16 MB)  -> X1             (live 7..9)
//  WD1 (split de1_w, 512 KB)     -> x_pred region  (live 10..12; de2p@14 kills)
//  WD2 (split de2_w, 128 KB)     -> X0 base        (live 13..14)
//  1 split8; 2 ex1 in_seq->X0; 3 ex2 X0->X1; 4 ex3 X1->X0(x_seq);
//  5 de1r X0->X1; 6 de2r X1->x_recon; 7 ez1 in_seq->Z0; 8 ez2 Z0->Z1;
//  9 ez3 Z1->z_seq; 10 split de1_w->WD1; 11 scan X0 in-place + z_pred;
//  12 de1p X0->X1 (B=WD1); 13 split de2_w->WD2; 14 de2p X1->x_pred (B=WD2)
// ---------------------------------------------------------------------------
extern "C" void kernel_launch(void* const* d_in, const int* in_sizes, int n_in,
                              void* d_out, int out_size, void* d_ws,
                              size_t ws_size, hipStream_t stream) {
  const float* in_seq = (const float*)d_in[0];
  const float* Lm    = (const float*)d_in[1];
  const float* Rm    = (const float*)d_in[2];
  const float* Wz    = (const float*)d_in[3];
  const float* Az_w  = (const float*)d_in[4];
  const float* Az_b  = (const float*)d_in[5];
  const float* ex1_w = (const float*)d_in[6];
  const float* ex1_b = (const float*)d_in[7];
  const float* ex2_w = (const float*)d_in[8];
  const float* ex2_b = (const float*)d_in[9];
  const float* ex3_w = (const float*)d_in[10];
  const float* ex3_b = (const float*)d_in[11];
  const float* ez1_w = (const float*)d_in[12];
  const float* ez1_b = (const float*)d_in[13];
  const float* ez2_w = (const float*)d_in[14];
  const float* ez2_b = (const float*)d_in[15];
  const float* ez3_w = (const float*)d_in[16];
  const float* ez3_b = (const float*)d_in[17];
  const float* de1_w = (const float*)d_in[18];
  const float* de1_b = (const float*)d_in[19];
  const float* de2_w = (const float*)d_in[20];
  const float* de2_b = (const float*)d_in[21];

  float* out = (float*)d_out;
  float* x_pred  = out;                                        // BT*P
  float* x_recon = out + (size_t)BT * P;                       // BT*P
  float* z_pred  = out + (size_t)2 * BT * P;                   // BT*M
  float* z_seq   = out + (size_t)2 * BT * P + (size_t)BT * M;  // BT*M

  float* X0 = (float*)d_ws;               // BT*K fp32 activations (64 MB)
  float* X1 = X0 + (size_t)BT * K;        // 64 MB
  float* Z0 = X1;                         // z activations inside X1 window
  float* Z1 = X1 + (size_t)BT * M;
  short* Wr  = (short*)z_pred;            // split-weight block in z_pred region
  short* WD1 = (short*)x_pred;            // de1 re-split (x_pred free till 14)
  short* WD2 = (short*)X0;                // de2 re-split (after X0 dies @12)

  // weight offsets in Wr (shorts): hi at hoff, lo at hoff + 4*n4
  const unsigned HO_EX1 = 0,      HO_EX2 = 65536,  HO_EX3 = 196608;
  const unsigned HO_DE1 = 327680, HO_DE2 = 458752;
  const unsigned HO_EZ1 = 524288, HO_EZ2 = 540672, HO_EZ3 = 548864;

  const dim3 blk(256);
  const dim3 gx(BT / 128, 2);    // KOUT=256, BN=128
  const dim3 g128(BT / 128, 1);  // KOUT=128
  const dim3 g64(BT / 128, 1);   // KOUT=64, BN=64

  // 1: split all 8 weights into Wr
  W8 w8;
  w8.src[0] = ex1_w; w8.hoff[0] = HO_EX1; w8.n4[0] = 8192;
  w8.src[1] = ex2_w; w8.hoff[1] = HO_EX2; w8.n4[1] = 16384;
  w8.src[2] = ex3_w; w8.hoff[2] = HO_EX3; w8.n4[2] = 16384;
  w8.src[3] = de1_w; w8.hoff[3] = HO_DE1; w8.n4[3] = 16384;
  w8.src[4] = de2_w; w8.hoff[4] = HO_DE2; w8.n4[4] = 8192;
  w8.src[5] = ez1_w; w8.hoff[5] = HO_EZ1; w8.n4[5] = 2048;
  w8.src[6] = ez2_w; w8.hoff[6] = HO_EZ2; w8.n4[6] = 1024;
  w8.src[7] = ez3_w; w8.hoff[7] = HO_EZ3; w8.n4[7] = 1024;
  split8_kernel<<<dim3(64, 8), blk, 0, stream>>>(w8, Wr);

  // 2-4: x encoder 128->256->256->256
  gemm_als<128, 256, 128><<<gx, blk, 0, stream>>>(
      in_seq, Wr + HO_EX1, Wr + HO_EX1 + 32768, ex1_b, X0);
  gemm_als<256, 256, 128><<<gx, blk, 0, stream>>>(
      X0, Wr + HO_EX2, Wr + HO_EX2 + 65536, ex2_b, X1);
  gemm_als<256, 256, 128><<<gx, blk, 0, stream>>>(
      X1, Wr + HO_EX3, Wr + HO_EX3 + 65536, ex3_b, X0);
  // 5-6: x_recon decoder
  gemm_als<256, 256, 128><<<gx, blk, 0, stream>>>(
      X0, Wr + HO_DE1, Wr + HO_DE1 + 65536, de1_b, X1);
  gemm_als<256, 128, 128><<<g128, blk, 0, stream>>>(
      X1, Wr + HO_DE2, Wr + HO_DE2 + 32768, de2_b, x_recon);
  // 7-9: z encoder 128->64->64->64
  gemm_als<128, 64, 64><<<g64, blk, 0, stream>>>(
      in_seq, Wr + HO_EZ1, Wr + HO_EZ1 + 8192, ez1_b, Z0);
  gemm_als<64, 64, 64><<<g64, blk, 0, stream>>>(
      Z0, Wr + HO_EZ2, Wr + HO_EZ2 + 4096, ez2_b, Z1);
  gemm_als<64, 64, 64><<<g64, blk, 0, stream>>>(
      Z1, Wr + HO_EZ3, Wr + HO_EZ3 + 4096, ez3_b, z_seq);
  // 10: split de1_w into x_pred region (z_pred/Wr dies at scan)
  split_kernel<<<dim3(64), blk, 0, stream>>>(de1_w, WD1, WD1 + 65536, 16384);
  // 11: scan (in-place on X0), z_pred out
  scan_kernel<<<dim3(B * NSEG / 8), dim3(512), 0, stream>>>(
      X0, z_seq, Lm, Rm, Wz, Az_w, Az_b, z_pred);
  // 12: de1p X0 -> X1
  gemm_als<256, 256, 128><<<gx, blk, 0, stream>>>(
      X0, WD1, WD1 + 65536, de1_b, X1);
  // 13: split de2_w into dead X0 head
  split_kernel<<<dim3(32), blk, 0, stream>>>(de2_w, WD2, WD2 + 32768, 8192);
  // 14: de2p X1 -> x_pred
  gemm_als<256, 128, 128><<<g128, blk, 0, stream>>>(
      X1, WD2, WD2 + 32768, de2_b, x_pred);
}